// Round 4
// baseline (196.620 us; speedup 1.0000x reference)
//
#include <hip/hip_runtime.h>
#include <math.h>

// ---------------------------------------------------------------------------
// RotSSM: out[b,Do,t] = C2 @ scan(M @ u)[.,b,t] + D ⊙ u[b,.,t]
//   k0 (64 blocks, one head each): trace (float4 + shuffle reduce), expm,
//      gamma/norm, complex power tables, then M = norm*(P@B) and
//      C2 = C@blockdiag(P^T) for this head's rows/cols. Serial double-prec
//      pieces (expm / tables / norm) live in DIFFERENT waves so they overlap.
//   k1 (128x8 blocks, LCH=32): stage u tile -> MFMA GEMM1 -> local scan in
//      LDS -> chunk totals to global (1 MB). NO state array.
//   k3 (128x8 blocks): RECOMPUTES stage+GEMM1+scan (identical math), then
//      closed-form carry from totals (t-split, 256 thr) -> corrected z in
//      LDS -> MFMA GEMM2 -> out + D⊙u.
//   Workspace total ~1.5 MB (was 18 MB with the state round-trip); HBM
//   traffic drops ~33 MB. 1024 blocks = 4 blocks/CU (launch_bounds(256,4)).
// ---------------------------------------------------------------------------

typedef __attribute__((ext_vector_type(8))) short short8;   // 8 bf16 (4 VGPRs)
typedef __attribute__((ext_vector_type(4))) float f32x4;

#define TLEN 4096
#define LCH 32            // chunk length (t per block)
#define NCH 128           // number of chunks
#define BSZ 8
#define LDK 264           // shorts per [t] row (256 + 8 pad, keeps 16B align)
#define LDW 132           // dwords per [t] row (= LDK/2)

// workspace float offsets
constexpr int MB_OFF   = 0;                               // M bf16 [256][256]
constexpr int CB_OFF   = 32768;                           // C2 bf16 [256][256]
constexpr int AP_OFF   = 65536;                           // Apow  [LCH+1][128] float2
constexpr int ALP_OFF  = AP_OFF + (LCH + 1) * 256;        // ALpow [NCH+1][128] float2
constexpr int TOT_OFF  = ALP_OFF + (NCH + 1) * 256;       // Tot [NCH][8][128] float2
// end = TOT_OFF + NCH*BSZ*256 = 369152 floats ~ 1.48 MB

__device__ __forceinline__ float bfbits2f(unsigned int bits16) {
  union { unsigned int u; float f; } v; v.u = bits16 << 16; return v.f;
}
__device__ __forceinline__ unsigned int f2bfbits(float f) {
  union { float f; unsigned int u; } v; v.f = f;
  return (v.u + 0x7fffu + ((v.u >> 16) & 1u)) >> 16;   // RNE, finite inputs
}
__device__ __forceinline__ unsigned int pack2(float x, float y) {
  return f2bfbits(x) | (f2bfbits(y) << 16);
}

// ---------------------------------------------------------------------------
// K0: one block per head. trace -> {expm | tables | norm in separate waves}
//     -> M rows 4h..4h+3 and C2 cols 4h..4h+3.
// ---------------------------------------------------------------------------
__global__ __launch_bounds__(256) void k0_setup(
    const float* __restrict__ thetas_log, const float* __restrict__ P_param,
    const float* __restrict__ B_param, const float* __restrict__ C,
    const float* __restrict__ gamma_log, float* __restrict__ ws) {
  const int h = blockIdx.x;
  const int tid = threadIdx.x;
  __shared__ float red[4];
  __shared__ float Psh[16];
  __shared__ float nrmsh;

  {
    // B_param head h = 4 rows x 256 = 1024 floats; one float4 per thread.
    float4 v = *(const float4*)(B_param + (size_t)h * 1024 + tid * 4);
    float s = v.x * v.x + v.y * v.y + v.z * v.z + v.w * v.w;
#pragma unroll
    for (int off = 32; off > 0; off >>= 1) s += __shfl_down(s, off);
    if ((tid & 63) == 0) red[tid >> 6] = s;
  }
  __syncthreads();

  if (tid == 0) {
    // expm(skew(P_param[h])) -> Psh (wave 0)
    double A[4][4], E[4][4], Tm[4][4];
    for (int i = 0; i < 4; ++i)
      for (int j = 0; j < 4; ++j)
        A[i][j] = (double)P_param[h * 16 + i * 4 + j] - (double)P_param[h * 16 + j * 4 + i];
    double fro = 0.0;
    for (int i = 0; i < 4; ++i) for (int j = 0; j < 4; ++j) fro += A[i][j] * A[i][j];
    fro = sqrt(fro);
    int s = 0;
    while (fro > 0.25 && s < 30) { fro *= 0.5; ++s; }
    double scl = 1.0;
    for (int q2 = 0; q2 < s; ++q2) scl *= 0.5;
    for (int i = 0; i < 4; ++i) for (int j = 0; j < 4; ++j) A[i][j] *= scl;
    for (int i = 0; i < 4; ++i)
      for (int j = 0; j < 4; ++j) { E[i][j] = (i == j) ? 1.0 : 0.0; Tm[i][j] = E[i][j]; }
    for (int k = 1; k <= 16; ++k) {
      double Tn[4][4];
      for (int i = 0; i < 4; ++i)
        for (int j = 0; j < 4; ++j) {
          double acc = 0.0;
          for (int m = 0; m < 4; ++m) acc += Tm[i][m] * A[m][j];
          Tn[i][j] = acc / (double)k;
        }
      for (int i = 0; i < 4; ++i)
        for (int j = 0; j < 4; ++j) { Tm[i][j] = Tn[i][j]; E[i][j] += Tn[i][j]; }
    }
    for (int q2 = 0; q2 < s; ++q2) {
      double E2[4][4];
      for (int i = 0; i < 4; ++i)
        for (int j = 0; j < 4; ++j) {
          double acc = 0.0;
          for (int m = 0; m < 4; ++m) acc += E[i][m] * E[m][j];
          E2[i][j] = acc;
        }
      for (int i = 0; i < 4; ++i) for (int j = 0; j < 4; ++j) E[i][j] = E2[i][j];
    }
    for (int i = 0; i < 4; ++i)
      for (int j = 0; j < 4; ++j) Psh[i * 4 + j] = (float)E[i][j];
  } else if (tid == 64 || tid == 65) {
    // power tables (wave 1) — needs only gamma & theta
    const int p = h * 2 + (tid - 64);
    double th = exp((double)thetas_log[p]);
    double g = exp(-exp((double)gamma_log[h]));
    double ar = g * cos(th), ai = g * sin(th);
    float2* Apw = (float2*)(ws + AP_OFF);
    float2* ALp = (float2*)(ws + ALP_OFF);
    double xr = 1.0, xi = 0.0;
    Apw[p] = make_float2(1.f, 0.f);
    for (int j = 1; j <= LCH; ++j) {
      double nr = xr * ar - xi * ai, ni = xr * ai + xi * ar;
      xr = nr; xi = ni;
      Apw[j * 128 + p] = make_float2((float)xr, (float)xi);
    }
    double br = xr, bi = xi;   // a^LCH
    xr = 1.0; xi = 0.0;
    ALp[p] = make_float2(1.f, 0.f);
    for (int k = 1; k <= NCH; ++k) {
      double nr = xr * br - xi * bi, ni = xr * bi + xi * br;
      xr = nr; xi = ni;
      ALp[k * 128 + p] = make_float2((float)xr, (float)xi);
    }
  } else if (tid == 128) {
    // norm (wave 2)
    double g = exp(-exp((double)gamma_log[h]));
    double tr = (double)red[0] + red[1] + red[2] + red[3];
    nrmsh = (float)sqrt((1.0 - g * g) / tr);
  }
  __syncthreads();

  // ---- M rows 4h..4h+3 (col = tid), C2 cols 4h..4h+3 (row Do = tid) ----
  unsigned short* Mbf = (unsigned short*)(ws + MB_OFF);
  unsigned int*   Cbd = (unsigned int*)(ws + CB_OFF);
  {
    float b0 = B_param[(h * 4 + 0) * 256 + tid];
    float b1 = B_param[(h * 4 + 1) * 256 + tid];
    float b2 = B_param[(h * 4 + 2) * 256 + tid];
    float b3 = B_param[(h * 4 + 3) * 256 + tid];
    float nrm = nrmsh;
#pragma unroll
    for (int N = 0; N < 4; ++N) {
      float acc = Psh[N * 4 + 0] * b0 + Psh[N * 4 + 1] * b1 +
                  Psh[N * 4 + 2] * b2 + Psh[N * 4 + 3] * b3;
      Mbf[(h * 4 + N) * 256 + tid] = (unsigned short)f2bfbits(nrm * acc);
    }
  }
  {
    float4 cv = *(const float4*)(C + (size_t)tid * 256 + h * 4);
    float o[4];
#pragma unroll
    for (int N = 0; N < 4; ++N)
      o[N] = cv.x * Psh[N * 4 + 0] + cv.y * Psh[N * 4 + 1] +
             cv.z * Psh[N * 4 + 2] + cv.w * Psh[N * 4 + 3];
    Cbd[(tid * 256 + h * 4) >> 1]       = pack2(o[0], o[1]);
    Cbd[((tid * 256 + h * 4) >> 1) + 1] = pack2(o[2], o[3]);
  }
}

// ---------------------------------------------------------------------------
// Shared device helpers for k1/k3: stage + GEMM1 + pack + local scan.
// ---------------------------------------------------------------------------
__device__ __forceinline__ void stage_gemm1_scan(
    const float* __restrict__ u, const float* __restrict__ ws,
    unsigned char* smem, int c, int b, int tid,
    float* zr_out, float* zi_out) {
  unsigned short* us = (unsigned short*)smem;   // u tile [t][LDK]
  unsigned int*   wd = (unsigned int*)smem;     // W/scan [t][LDW] dwords
  const int t0 = c * LCH;
  const int L = tid & 63;
  const int w = __builtin_amdgcn_readfirstlane(tid >> 6);
  const int qh = L >> 4, l15 = L & 15;

  // ---- stage u[d][t0+t] -> us[t][d ^ ((t&3)<<3)] ----
  {
    const int dg = tid >> 3;                // 0..31
    const int t4 = (tid & 7) * 4;           // 0..28
#pragma unroll
    for (int i = 0; i < 8; ++i) {
      int d = dg + i * 32;
      float4 v = *(const float4*)(u + (size_t)(b * 256 + d) * TLEN + t0 + t4);
      float vv[4] = {v.x, v.y, v.z, v.w};
#pragma unroll
      for (int dt = 0; dt < 4; ++dt) {
        int t = t4 + dt;
        us[t * LDK + (d ^ ((t & 3) << 3))] = (unsigned short)f2bfbits(vv[dt]);
      }
    }
  }
  __syncthreads();

  // ---- GEMM1: W[256][32] = M @ u_tile ----
  f32x4 acc[4][2];
#pragma unroll
  for (int rt = 0; rt < 4; ++rt)
#pragma unroll
    for (int tt = 0; tt < 2; ++tt) acc[rt][tt] = (f32x4){0.f, 0.f, 0.f, 0.f};
  {
    const unsigned short* Mbf = (const unsigned short*)(ws + MB_OFF);
#pragma unroll
    for (int ks = 0; ks < 8; ++ks) {
      short8 af[4], bf[2];
#pragma unroll
      for (int rt = 0; rt < 4; ++rt)
        af[rt] = *(const short8*)(Mbf + (size_t)(w * 64 + rt * 16 + l15) * 256 + ks * 32 + qh * 8);
#pragma unroll
      for (int tt = 0; tt < 2; ++tt) {
        int row = tt * 16 + l15;
        int col = (ks * 32 + qh * 8) ^ ((row & 3) << 3);
        bf[tt] = *(const short8*)(us + row * LDK + col);
      }
#pragma unroll
      for (int rt = 0; rt < 4; ++rt)
#pragma unroll
        for (int tt = 0; tt < 2; ++tt)
          acc[rt][tt] = __builtin_amdgcn_mfma_f32_16x16x32_bf16(af[rt], bf[tt], acc[rt][tt], 0, 0, 0);
    }
  }
  __syncthreads();   // all us reads done before overwrite (alias)

  // ---- W -> wd[t][p] pair-packed bf16 (D: row=qh*4+q, col=l15) ----
#pragma unroll
  for (int rt = 0; rt < 4; ++rt) {
    int pbase = w * 32 + rt * 8 + qh * 2;   // dword index = state-row/2
#pragma unroll
    for (int tt = 0; tt < 2; ++tt) {
      int t = tt * 16 + l15;
      f32x4 a4 = acc[rt][tt];
      wd[t * LDW + pbase]     = pack2(a4[0], a4[1]);
      wd[t * LDW + pbase + 1] = pack2(a4[2], a4[3]);
    }
  }
  __syncthreads();

  // ---- local scan (fp32 state, bf16 storage) ----
  float zr = 0.f, zi = 0.f;
  if (tid < 128) {
    const int p = tid;
    const float2* Apw = (const float2*)(ws + AP_OFF);
    float2 a = Apw[128 + p];       // a^1
#pragma unroll
    for (int t = 0; t < LCH; ++t) {
      unsigned int wv = wd[t * LDW + p];
      float wr = bfbits2f(wv & 0xffffu), wi = bfbits2f(wv >> 16);
      float nr = fmaf(a.x, zr, fmaf(-a.y, zi, wr));
      float ni = fmaf(a.x, zi, fmaf(a.y, zr, wi));
      zr = nr; zi = ni;
      wd[t * LDW + p] = pack2(zr, zi);
    }
  }
  *zr_out = zr; *zi_out = zi;
}

// ---------------------------------------------------------------------------
// K1: stage -> GEMM1 -> scan -> chunk totals to global. No state write.
// ---------------------------------------------------------------------------
__global__ __launch_bounds__(256, 4) void k1_mfma(
    const float* __restrict__ u, float* __restrict__ ws) {
  __shared__ __align__(16) unsigned char smem[LCH * LDK * 2];   // 16896 B
  const int c = blockIdx.x, b = blockIdx.y;
  const int tid = threadIdx.x;
  float zr, zi;
  stage_gemm1_scan(u, ws, smem, c, b, tid, &zr, &zi);
  if (tid < 128)
    ((float2*)(ws + TOT_OFF))[(c * BSZ + b) * 128 + tid] = make_float2(zr, zi);
}

// ---------------------------------------------------------------------------
// K3: recompute stage+GEMM1+scan -> carry from totals (t-split) -> z tile
//     -> MFMA GEMM2 -> out + D⊙u.
// ---------------------------------------------------------------------------
__global__ __launch_bounds__(256, 4) void k3_mfma(
    const float* __restrict__ u, const float* __restrict__ Dv,
    const float* __restrict__ ws, float* __restrict__ out) {
  __shared__ __align__(16) unsigned char smem[LCH * LDK * 2];
  unsigned int* wd = (unsigned int*)smem;       // local-z tile [t][LDW] dwords

  const int c = blockIdx.x, b = blockIdx.y;
  const int t0 = c * LCH;
  const int tid = threadIdx.x;
  const int L = tid & 63;
  const int w = __builtin_amdgcn_readfirstlane(tid >> 6);
  const int qh = L >> 4, l15 = L & 15;

  float zr_dummy, zi_dummy;
  stage_gemm1_scan(u, ws, smem, c, b, tid, &zr_dummy, &zi_dummy);
  __syncthreads();   // local-z in wd visible to all threads

  // ---- carry (closed form, per p; both t-halves redundantly) + correct ----
  {
    const int p = tid & 127;
    const int thalf = (tid >> 7) * 16;     // 0-127: t 0..15; 128-255: t 16..31
    float cr = 0.f, ci = 0.f;
    const float2* ALp = (const float2*)(ws + ALP_OFF);
    const float2* Tot = (const float2*)(ws + TOT_OFF);
    for (int cp = 0; cp < c; ++cp) {
      float2 al = ALp[(c - 1 - cp) * 128 + p];
      float2 tv = Tot[(cp * BSZ + b) * 128 + p];
      cr = fmaf(al.x, tv.x, fmaf(-al.y, tv.y, cr));
      ci = fmaf(al.x, tv.y, fmaf(al.y, tv.x, ci));
    }
    const float2* Apw = (const float2*)(ws + AP_OFF);
#pragma unroll
    for (int tt2 = 0; tt2 < 16; ++tt2) {
      int t = thalf + tt2;
      unsigned int wv = wd[t * LDW + p];
      float2 ap = Apw[(t + 1) * 128 + p];
      float sr = fmaf(ap.x, cr, fmaf(-ap.y, ci, bfbits2f(wv & 0xffffu)));
      float si = fmaf(ap.x, ci, fmaf(ap.y, cr, bfbits2f(wv >> 16)));
      wd[t * LDW + p] = pack2(sr, si);
    }
  }
  __syncthreads();

  // ---- GEMM2: out_tile = C2 @ Z ----
  f32x4 acc[4][2];
#pragma unroll
  for (int rt = 0; rt < 4; ++rt)
#pragma unroll
    for (int tt = 0; tt < 2; ++tt) acc[rt][tt] = (f32x4){0.f, 0.f, 0.f, 0.f};
  {
    const unsigned short* Cbf = (const unsigned short*)(ws + CB_OFF);
    const unsigned short* zs  = (const unsigned short*)smem;
#pragma unroll
    for (int ks = 0; ks < 8; ++ks) {
      short8 af[4], bf[2];
#pragma unroll
      for (int rt = 0; rt < 4; ++rt)
        af[rt] = *(const short8*)(Cbf + (size_t)(w * 64 + rt * 16 + l15) * 256 + ks * 32 + qh * 8);
#pragma unroll
      for (int tt = 0; tt < 2; ++tt)
        bf[tt] = *(const short8*)(zs + (tt * 16 + l15) * LDK + ks * 32 + qh * 8);
#pragma unroll
      for (int rt = 0; rt < 4; ++rt)
#pragma unroll
        for (int tt = 0; tt < 2; ++tt)
          acc[rt][tt] = __builtin_amdgcn_mfma_f32_16x16x32_bf16(af[rt], bf[tt], acc[rt][tt], 0, 0, 0);
    }
  }

  // ---- epilogue: out = acc + D ⊙ u ----
  float dv[4][4];
#pragma unroll
  for (int rt = 0; rt < 4; ++rt)
#pragma unroll
    for (int q = 0; q < 4; ++q) dv[rt][q] = Dv[w * 64 + rt * 16 + qh * 4 + q];
#pragma unroll
  for (int rt = 0; rt < 4; ++rt) {
    int Dbase = w * 64 + rt * 16 + qh * 4;
#pragma unroll
    for (int tt = 0; tt < 2; ++tt) {
      int t = tt * 16 + l15;
      f32x4 a4 = acc[rt][tt];
      size_t obase = (size_t)(b * 256 + Dbase) * TLEN + t0 + t;
#pragma unroll
      for (int q = 0; q < 4; ++q)
        out[obase + (size_t)q * TLEN] = a4[q] + dv[rt][q] * u[obase + (size_t)q * TLEN];
    }
  }
}

extern "C" void kernel_launch(void* const* d_in, const int* in_sizes, int n_in,
                              void* d_out, int out_size, void* d_ws, size_t ws_size,
                              hipStream_t stream) {
  const float* u          = (const float*)d_in[0];
  const float* thetas_log = (const float*)d_in[1];
  const float* P_param    = (const float*)d_in[2];
  const float* B_param    = (const float*)d_in[3];
  const float* C          = (const float*)d_in[4];
  const float* Dvec       = (const float*)d_in[5];
  const float* gamma_log  = (const float*)d_in[6];
  float* out = (float*)d_out;
  float* ws  = (float*)d_ws;

  hipLaunchKernelGGL(k0_setup, dim3(64), dim3(256), 0, stream,
                     thetas_log, P_param, B_param, C, gamma_log, ws);
  hipLaunchKernelGGL(k1_mfma, dim3(NCH, BSZ), dim3(256), 0, stream, u, ws);
  hipLaunchKernelGGL(k3_mfma, dim3(NCH, BSZ), dim3(256), 0, stream, u, Dvec, ws, out);
}

// Round 5
// 182.814 us; speedup vs baseline: 1.0755x; 1.0755x over previous
//
#include <hip/hip_runtime.h>
#include <math.h>

// ---------------------------------------------------------------------------
// RotSSM: out[b,Do,t] = C2 @ scan(M @ u)[.,b,t] + D ⊙ u[b,.,t]
//   k0 (64 blocks, one head each): trace/expm/norm/power tables + M, C2.
//   k1 (128x8 blocks, LCH=32): stage u tile (dword-pair writes) -> MFMA
//      GEMM1 -> local scan in LDS -> Zst (per-block-contiguous 16KB bf16
//      states, coalesced) + chunk totals to global.
//   k3 (128x8 blocks): coalesced Zst reload -> LDS, closed-form carry from
//      totals (t-split, 256 thr) -> corrected z -> MFMA GEMM2 -> out + D⊙u.
//   NO recompute (round-4 regression), NO scattered state reads (round-0
//   latency trap). 1024 blocks = 4 blocks/CU (launch_bounds(256,4)).
// ---------------------------------------------------------------------------

typedef __attribute__((ext_vector_type(8))) short short8;   // 8 bf16 (4 VGPRs)
typedef __attribute__((ext_vector_type(4))) float f32x4;

#define TLEN 4096
#define LCH 32            // chunk length (t per block)
#define NCH 128           // number of chunks
#define BSZ 8
#define LDW 132           // dwords per [t] row (128 + 4 pad)
#define LDK 264           // shorts per [t] row (= LDW*2)

// workspace float offsets
constexpr int MB_OFF   = 0;                               // M bf16 [256][256]
constexpr int CB_OFF   = 32768;                           // C2 bf16 [256][256]
constexpr int AP_OFF   = 65536;                           // Apow  [LCH+1][128] float2
constexpr int ALP_OFF  = AP_OFF + (LCH + 1) * 256;        // ALpow [NCH+1][128] float2
constexpr int TOT_OFF  = ALP_OFF + (NCH + 1) * 256;       // Tot [NCH][8][128] float2
constexpr int ZST_OFF  = TOT_OFF + NCH * BSZ * 256;       // Zst [NCH*8][4096] dwords
// end = ZST_OFF + 1024*4096 = 4563456 floats ~ 18.3 MB

__device__ __forceinline__ float bfbits2f(unsigned int bits16) {
  union { unsigned int u; float f; } v; v.u = bits16 << 16; return v.f;
}
__device__ __forceinline__ unsigned int f2bfbits(float f) {
  union { float f; unsigned int u; } v; v.f = f;
  return (v.u + 0x7fffu + ((v.u >> 16) & 1u)) >> 16;   // RNE, finite inputs
}
__device__ __forceinline__ unsigned int pack2(float x, float y) {
  return f2bfbits(x) | (f2bfbits(y) << 16);
}

// ---------------------------------------------------------------------------
// K0: one block per head. trace -> {expm | tables | norm in separate waves}
//     -> M rows 4h..4h+3 and C2 cols 4h..4h+3.  (verified round 4)
// ---------------------------------------------------------------------------
__global__ __launch_bounds__(256) void k0_setup(
    const float* __restrict__ thetas_log, const float* __restrict__ P_param,
    const float* __restrict__ B_param, const float* __restrict__ C,
    const float* __restrict__ gamma_log, float* __restrict__ ws) {
  const int h = blockIdx.x;
  const int tid = threadIdx.x;
  __shared__ float red[4];
  __shared__ float Psh[16];
  __shared__ float nrmsh;

  {
    float4 v = *(const float4*)(B_param + (size_t)h * 1024 + tid * 4);
    float s = v.x * v.x + v.y * v.y + v.z * v.z + v.w * v.w;
#pragma unroll
    for (int off = 32; off > 0; off >>= 1) s += __shfl_down(s, off);
    if ((tid & 63) == 0) red[tid >> 6] = s;
  }
  __syncthreads();

  if (tid == 0) {
    double A[4][4], E[4][4], Tm[4][4];
    for (int i = 0; i < 4; ++i)
      for (int j = 0; j < 4; ++j)
        A[i][j] = (double)P_param[h * 16 + i * 4 + j] - (double)P_param[h * 16 + j * 4 + i];
    double fro = 0.0;
    for (int i = 0; i < 4; ++i) for (int j = 0; j < 4; ++j) fro += A[i][j] * A[i][j];
    fro = sqrt(fro);
    int s = 0;
    while (fro > 0.25 && s < 30) { fro *= 0.5; ++s; }
    double scl = 1.0;
    for (int q2 = 0; q2 < s; ++q2) scl *= 0.5;
    for (int i = 0; i < 4; ++i) for (int j = 0; j < 4; ++j) A[i][j] *= scl;
    for (int i = 0; i < 4; ++i)
      for (int j = 0; j < 4; ++j) { E[i][j] = (i == j) ? 1.0 : 0.0; Tm[i][j] = E[i][j]; }
    for (int k = 1; k <= 16; ++k) {
      double Tn[4][4];
      for (int i = 0; i < 4; ++i)
        for (int j = 0; j < 4; ++j) {
          double acc = 0.0;
          for (int m = 0; m < 4; ++m) acc += Tm[i][m] * A[m][j];
          Tn[i][j] = acc / (double)k;
        }
      for (int i = 0; i < 4; ++i)
        for (int j = 0; j < 4; ++j) { Tm[i][j] = Tn[i][j]; E[i][j] += Tn[i][j]; }
    }
    for (int q2 = 0; q2 < s; ++q2) {
      double E2[4][4];
      for (int i = 0; i < 4; ++i)
        for (int j = 0; j < 4; ++j) {
          double acc = 0.0;
          for (int m = 0; m < 4; ++m) acc += E[i][m] * E[m][j];
          E2[i][j] = acc;
        }
      for (int i = 0; i < 4; ++i) for (int j = 0; j < 4; ++j) E[i][j] = E2[i][j];
    }
    for (int i = 0; i < 4; ++i)
      for (int j = 0; j < 4; ++j) Psh[i * 4 + j] = (float)E[i][j];
  } else if (tid == 64 || tid == 65) {
    const int p = h * 2 + (tid - 64);
    double th = exp((double)thetas_log[p]);
    double g = exp(-exp((double)gamma_log[h]));
    double ar = g * cos(th), ai = g * sin(th);
    float2* Apw = (float2*)(ws + AP_OFF);
    float2* ALp = (float2*)(ws + ALP_OFF);
    double xr = 1.0, xi = 0.0;
    Apw[p] = make_float2(1.f, 0.f);
    for (int j = 1; j <= LCH; ++j) {
      double nr = xr * ar - xi * ai, ni = xr * ai + xi * ar;
      xr = nr; xi = ni;
      Apw[j * 128 + p] = make_float2((float)xr, (float)xi);
    }
    double br = xr, bi = xi;   // a^LCH
    xr = 1.0; xi = 0.0;
    ALp[p] = make_float2(1.f, 0.f);
    for (int k = 1; k <= NCH; ++k) {
      double nr = xr * br - xi * bi, ni = xr * bi + xi * br;
      xr = nr; xi = ni;
      ALp[k * 128 + p] = make_float2((float)xr, (float)xi);
    }
  } else if (tid == 128) {
    double g = exp(-exp((double)gamma_log[h]));
    double tr = (double)red[0] + red[1] + red[2] + red[3];
    nrmsh = (float)sqrt((1.0 - g * g) / tr);
  }
  __syncthreads();

  unsigned short* Mbf = (unsigned short*)(ws + MB_OFF);
  unsigned int*   Cbd = (unsigned int*)(ws + CB_OFF);
  {
    float b0 = B_param[(h * 4 + 0) * 256 + tid];
    float b1 = B_param[(h * 4 + 1) * 256 + tid];
    float b2 = B_param[(h * 4 + 2) * 256 + tid];
    float b3 = B_param[(h * 4 + 3) * 256 + tid];
    float nrm = nrmsh;
#pragma unroll
    for (int N = 0; N < 4; ++N) {
      float acc = Psh[N * 4 + 0] * b0 + Psh[N * 4 + 1] * b1 +
                  Psh[N * 4 + 2] * b2 + Psh[N * 4 + 3] * b3;
      Mbf[(h * 4 + N) * 256 + tid] = (unsigned short)f2bfbits(nrm * acc);
    }
  }
  {
    float4 cv = *(const float4*)(C + (size_t)tid * 256 + h * 4);
    float o[4];
#pragma unroll
    for (int N = 0; N < 4; ++N)
      o[N] = cv.x * Psh[N * 4 + 0] + cv.y * Psh[N * 4 + 1] +
             cv.z * Psh[N * 4 + 2] + cv.w * Psh[N * 4 + 3];
    Cbd[(tid * 256 + h * 4) >> 1]       = pack2(o[0], o[1]);
    Cbd[((tid * 256 + h * 4) >> 1) + 1] = pack2(o[2], o[3]);
  }
}

// ---------------------------------------------------------------------------
// K1: stage u (dword-pair) -> GEMM1 -> scan -> Zst (coalesced) + totals.
// ---------------------------------------------------------------------------
__global__ __launch_bounds__(256, 4) void k1_mfma(
    const float* __restrict__ u, float* __restrict__ ws) {
  __shared__ __align__(16) unsigned char smem[LCH * LDK * 2];   // 16896 B
  unsigned short* us = (unsigned short*)smem;   // u tile [t][LDK] shorts
  unsigned int*   wd = (unsigned int*)smem;     // same, as [t][LDW] dwords

  const int c = blockIdx.x, b = blockIdx.y;
  const int t0 = c * LCH;
  const int tid = threadIdx.x;
  const int L = tid & 63;
  const int w = __builtin_amdgcn_readfirstlane(tid >> 6);
  const int qh = L >> 4, l15 = L & 15;

  // ---- stage u[d][t0+t] -> wd[t][j] (j = d/2, pair-packed, no swizzle) ----
  {
    const int dp = tid >> 3;                // 0..31
    const int t4 = (tid & 7) * 4;           // 0..28
#pragma unroll
    for (int i = 0; i < 4; ++i) {
      int j = dp + 32 * i;                  // pair index 0..127
      float4 va = *(const float4*)(u + (size_t)(b * 256 + 2 * j) * TLEN + t0 + t4);
      float4 vb = *(const float4*)(u + (size_t)(b * 256 + 2 * j + 1) * TLEN + t0 + t4);
      float av[4] = {va.x, va.y, va.z, va.w};
      float bv[4] = {vb.x, vb.y, vb.z, vb.w};
#pragma unroll
      for (int dt = 0; dt < 4; ++dt)
        wd[(t4 + dt) * LDW + j] = pack2(av[dt], bv[dt]);
    }
  }
  __syncthreads();

  // ---- GEMM1: W[256][32] = M @ u_tile ----
  f32x4 acc[4][2];
#pragma unroll
  for (int rt = 0; rt < 4; ++rt)
#pragma unroll
    for (int tt = 0; tt < 2; ++tt) acc[rt][tt] = (f32x4){0.f, 0.f, 0.f, 0.f};
  {
    const unsigned short* Mbf = (const unsigned short*)(ws + MB_OFF);
#pragma unroll
    for (int ks = 0; ks < 8; ++ks) {
      short8 af[4], bf[2];
#pragma unroll
      for (int rt = 0; rt < 4; ++rt)
        af[rt] = *(const short8*)(Mbf + (size_t)(w * 64 + rt * 16 + l15) * 256 + ks * 32 + qh * 8);
#pragma unroll
      for (int tt = 0; tt < 2; ++tt)
        bf[tt] = *(const short8*)(us + (tt * 16 + l15) * LDK + ks * 32 + qh * 8);
#pragma unroll
      for (int rt = 0; rt < 4; ++rt)
#pragma unroll
        for (int tt = 0; tt < 2; ++tt)
          acc[rt][tt] = __builtin_amdgcn_mfma_f32_16x16x32_bf16(af[rt], bf[tt], acc[rt][tt], 0, 0, 0);
    }
  }
  __syncthreads();   // all us reads done before overwrite (alias)

  // ---- W -> wd[t][p] pair-packed bf16 (D: row=qh*4+q, col=l15) ----
#pragma unroll
  for (int rt = 0; rt < 4; ++rt) {
    int pbase = w * 32 + rt * 8 + qh * 2;   // dword index = state-row/2
#pragma unroll
    for (int tt = 0; tt < 2; ++tt) {
      int t = tt * 16 + l15;
      f32x4 a4 = acc[rt][tt];
      wd[t * LDW + pbase]     = pack2(a4[0], a4[1]);
      wd[t * LDW + pbase + 1] = pack2(a4[2], a4[3]);
    }
  }
  __syncthreads();

  // ---- local scan (fp32 state, bf16 storage), totals ----
  if (tid < 128) {
    const int p = tid;
    const float2* Apw = (const float2*)(ws + AP_OFF);
    float2 a = Apw[128 + p];       // a^1
    float zr = 0.f, zi = 0.f;
#pragma unroll
    for (int t = 0; t < LCH; ++t) {
      unsigned int wv = wd[t * LDW + p];
      float wr = bfbits2f(wv & 0xffffu), wi = bfbits2f(wv >> 16);
      float nr = fmaf(a.x, zr, fmaf(-a.y, zi, wr));
      float ni = fmaf(a.x, zi, fmaf(a.y, zr, wi));
      zr = nr; zi = ni;
      wd[t * LDW + p] = pack2(zr, zi);
    }
    ((float2*)(ws + TOT_OFF))[(c * BSZ + b) * 128 + p] = make_float2(zr, zi);
  }
  __syncthreads();

  // ---- local-z states -> Zst (per-block contiguous, coalesced) ----
  unsigned int* Zg = (unsigned int*)(ws + ZST_OFF) + (size_t)(c * BSZ + b) * 4096;
#pragma unroll
  for (int jj = 0; jj < 16; ++jj) {
    int idx = tid + 256 * jj;
    Zg[idx] = wd[(idx >> 7) * LDW + (idx & 127)];
  }
}

// ---------------------------------------------------------------------------
// K3: coalesced Zst reload -> carry from totals (t-split) -> correct ->
//     MFMA GEMM2 -> out + D⊙u.
// ---------------------------------------------------------------------------
__global__ __launch_bounds__(256, 4) void k3_mfma(
    const float* __restrict__ u, const float* __restrict__ Dv,
    const float* __restrict__ ws, float* __restrict__ out) {
  __shared__ __align__(16) unsigned char smem[LCH * LDK * 2];
  unsigned int* wd = (unsigned int*)smem;       // z tile [t][LDW] dwords

  const int c = blockIdx.x, b = blockIdx.y;
  const int t0 = c * LCH;
  const int tid = threadIdx.x;
  const int L = tid & 63;
  const int w = __builtin_amdgcn_readfirstlane(tid >> 6);
  const int qh = L >> 4, l15 = L & 15;

  // ---- reload local-z states (coalesced dwords) ----
  {
    const unsigned int* Zg = (const unsigned int*)(ws + ZST_OFF) + (size_t)(c * BSZ + b) * 4096;
#pragma unroll
    for (int jj = 0; jj < 16; ++jj) {
      int idx = tid + 256 * jj;
      wd[(idx >> 7) * LDW + (idx & 127)] = Zg[idx];
    }
  }
  __syncthreads();

  // ---- carry (closed form, per p; both t-halves redundantly) + correct ----
  {
    const int p = tid & 127;
    const int thalf = (tid >> 7) * 16;     // 0-127: t 0..15; 128-255: t 16..31
    float cr = 0.f, ci = 0.f;
    const float2* ALp = (const float2*)(ws + ALP_OFF);
    const float2* Tot = (const float2*)(ws + TOT_OFF);
    for (int cp = 0; cp < c; ++cp) {
      float2 al = ALp[(c - 1 - cp) * 128 + p];
      float2 tv = Tot[(cp * BSZ + b) * 128 + p];
      cr = fmaf(al.x, tv.x, fmaf(-al.y, tv.y, cr));
      ci = fmaf(al.x, tv.y, fmaf(al.y, tv.x, ci));
    }
    const float2* Apw = (const float2*)(ws + AP_OFF);
#pragma unroll
    for (int tt2 = 0; tt2 < 16; ++tt2) {
      int t = thalf + tt2;
      unsigned int wv = wd[t * LDW + p];
      float2 ap = Apw[(t + 1) * 128 + p];
      float sr = fmaf(ap.x, cr, fmaf(-ap.y, ci, bfbits2f(wv & 0xffffu)));
      float si = fmaf(ap.x, ci, fmaf(ap.y, cr, bfbits2f(wv >> 16)));
      wd[t * LDW + p] = pack2(sr, si);
    }
  }
  __syncthreads();

  // ---- GEMM2: out_tile = C2 @ Z ----
  f32x4 acc[4][2];
#pragma unroll
  for (int rt = 0; rt < 4; ++rt)
#pragma unroll
    for (int tt = 0; tt < 2; ++tt) acc[rt][tt] = (f32x4){0.f, 0.f, 0.f, 0.f};
  {
    const unsigned short* Cbf = (const unsigned short*)(ws + CB_OFF);
    const unsigned short* zs  = (const unsigned short*)smem;
#pragma unroll
    for (int ks = 0; ks < 8; ++ks) {
      short8 af[4], bf[2];
#pragma unroll
      for (int rt = 0; rt < 4; ++rt)
        af[rt] = *(const short8*)(Cbf + (size_t)(w * 64 + rt * 16 + l15) * 256 + ks * 32 + qh * 8);
#pragma unroll
      for (int tt = 0; tt < 2; ++tt)
        bf[tt] = *(const short8*)(zs + (tt * 16 + l15) * LDK + ks * 32 + qh * 8);
#pragma unroll
      for (int rt = 0; rt < 4; ++rt)
#pragma unroll
        for (int tt = 0; tt < 2; ++tt)
          acc[rt][tt] = __builtin_amdgcn_mfma_f32_16x16x32_bf16(af[rt], bf[tt], acc[rt][tt], 0, 0, 0);
    }
  }

  // ---- epilogue: out = acc + D ⊙ u ----
  float dv[4][4];
#pragma unroll
  for (int rt = 0; rt < 4; ++rt)
#pragma unroll
    for (int q = 0; q < 4; ++q) dv[rt][q] = Dv[w * 64 + rt * 16 + qh * 4 + q];
#pragma unroll
  for (int rt = 0; rt < 4; ++rt) {
    int Dbase = w * 64 + rt * 16 + qh * 4;
#pragma unroll
    for (int tt = 0; tt < 2; ++tt) {
      int t = tt * 16 + l15;
      f32x4 a4 = acc[rt][tt];
      size_t obase = (size_t)(b * 256 + Dbase) * TLEN + t0 + t;
#pragma unroll
      for (int q = 0; q < 4; ++q)
        out[obase + (size_t)q * TLEN] = a4[q] + dv[rt][q] * u[obase + (size_t)q * TLEN];
    }
  }
}

extern "C" void kernel_launch(void* const* d_in, const int* in_sizes, int n_in,
                              void* d_out, int out_size, void* d_ws, size_t ws_size,
                              hipStream_t stream) {
  const float* u          = (const float*)d_in[0];
  const float* thetas_log = (const float*)d_in[1];
  const float* P_param    = (const float*)d_in[2];
  const float* B_param    = (const float*)d_in[3];
  const float* C          = (const float*)d_in[4];
  const float* Dvec       = (const float*)d_in[5];
  const float* gamma_log  = (const float*)d_in[6];
  float* out = (float*)d_out;
  float* ws  = (float*)d_ws;

  hipLaunchKernelGGL(k0_setup, dim3(64), dim3(256), 0, stream,
                     thetas_log, P_param, B_param, C, gamma_log, ws);
  hipLaunchKernelGGL(k1_mfma, dim3(NCH, BSZ), dim3(256), 0, stream, u, ws);
  hipLaunchKernelGGL(k3_mfma, dim3(NCH, BSZ), dim3(256), 0, stream, u, Dvec, ws, out);
}

// Round 7
// 172.524 us; speedup vs baseline: 1.1397x; 1.0596x over previous
//
#include <hip/hip_runtime.h>
#include <math.h>

// ---------------------------------------------------------------------------
// RotSSM: out[b,Do,t] = C2 @ scan(M @ u)[.,b,t] + D ⊙ u[b,.,t]
//   k0 (64 blocks, one head each): trace/expm/norm/Apow table + M, C2.
//   k1 (128x8 blocks, LCH=32): stage u tile (dword-pair) -> MFMA GEMM1 ->
//      local scan in LDS -> Zst (contiguous bf16 states) + chunk totals.
//   k2 (8 blocks x 128 thr): in-place EXCLUSIVE scan of Tot over chunks:
//      Tot[c] := Z_{c-1}  (carry entering chunk c). O(NCH) serial but tiny.
//   k3 (128x8 blocks): carry = ONE float2 load; fused reload+correct ->
//      LDS z tile -> MFMA GEMM2 -> out + D⊙u. No O(c) loop, no imbalance.
//   Workspace layout identical to round-5 proven footprint (~18.3 MB).
// ---------------------------------------------------------------------------

typedef __attribute__((ext_vector_type(8))) short short8;   // 8 bf16 (4 VGPRs)
typedef __attribute__((ext_vector_type(4))) float f32x4;

#define TLEN 4096
#define LCH 32            // chunk length (t per block)
#define NCH 128           // number of chunks
#define BSZ 8
#define LDW 132           // dwords per [t] row (128 + 4 pad)
#define LDK 264           // shorts per [t] row (= LDW*2)

// workspace float offsets (identical to round 5)
constexpr int MB_OFF   = 0;                               // M bf16 [256][256]
constexpr int CB_OFF   = 32768;                           // C2 bf16 [256][256]
constexpr int AP_OFF   = 65536;                           // Apow  [LCH+1][128] float2
constexpr int ALP_OFF  = AP_OFF + (LCH + 1) * 256;        // (unused, kept for layout)
constexpr int TOT_OFF  = ALP_OFF + (NCH + 1) * 256;       // Tot/Carry [NCH][8][128] float2
constexpr int ZST_OFF  = TOT_OFF + NCH * BSZ * 256;       // Zst [NCH*8][4096] dwords

__device__ __forceinline__ float bfbits2f(unsigned int bits16) {
  union { unsigned int u; float f; } v; v.u = bits16 << 16; return v.f;
}
__device__ __forceinline__ unsigned int f2bfbits(float f) {
  union { float f; unsigned int u; } v; v.f = f;
  return (v.u + 0x7fffu + ((v.u >> 16) & 1u)) >> 16;   // RNE, finite inputs
}
__device__ __forceinline__ unsigned int pack2(float x, float y) {
  return f2bfbits(x) | (f2bfbits(y) << 16);
}

// ---------------------------------------------------------------------------
// K0: one block per head. trace -> {expm | Apow table | norm, separate waves}
//     -> M rows 4h..4h+3 and C2 cols 4h..4h+3.  (ALp table no longer needed)
// ---------------------------------------------------------------------------
__global__ __launch_bounds__(256) void k0_setup(
    const float* __restrict__ thetas_log, const float* __restrict__ P_param,
    const float* __restrict__ B_param, const float* __restrict__ C,
    const float* __restrict__ gamma_log, float* __restrict__ ws) {
  const int h = blockIdx.x;
  const int tid = threadIdx.x;
  __shared__ float red[4];
  __shared__ float Psh[16];
  __shared__ float nrmsh;

  {
    float4 v = *(const float4*)(B_param + (size_t)h * 1024 + tid * 4);
    float s = v.x * v.x + v.y * v.y + v.z * v.z + v.w * v.w;
#pragma unroll
    for (int off = 32; off > 0; off >>= 1) s += __shfl_down(s, off);
    if ((tid & 63) == 0) red[tid >> 6] = s;
  }
  __syncthreads();

  if (tid == 0) {
    double A[4][4], E[4][4], Tm[4][4];
    for (int i = 0; i < 4; ++i)
      for (int j = 0; j < 4; ++j)
        A[i][j] = (double)P_param[h * 16 + i * 4 + j] - (double)P_param[h * 16 + j * 4 + i];
    double fro = 0.0;
    for (int i = 0; i < 4; ++i) for (int j = 0; j < 4; ++j) fro += A[i][j] * A[i][j];
    fro = sqrt(fro);
    int s = 0;
    while (fro > 0.25 && s < 30) { fro *= 0.5; ++s; }
    double scl = 1.0;
    for (int q2 = 0; q2 < s; ++q2) scl *= 0.5;
    for (int i = 0; i < 4; ++i) for (int j = 0; j < 4; ++j) A[i][j] *= scl;
    for (int i = 0; i < 4; ++i)
      for (int j = 0; j < 4; ++j) { E[i][j] = (i == j) ? 1.0 : 0.0; Tm[i][j] = E[i][j]; }
    for (int k = 1; k <= 16; ++k) {
      double Tn[4][4];
      for (int i = 0; i < 4; ++i)
        for (int j = 0; j < 4; ++j) {
          double acc = 0.0;
          for (int m = 0; m < 4; ++m) acc += Tm[i][m] * A[m][j];
          Tn[i][j] = acc / (double)k;
        }
      for (int i = 0; i < 4; ++i)
        for (int j = 0; j < 4; ++j) { Tm[i][j] = Tn[i][j]; E[i][j] += Tn[i][j]; }
    }
    for (int q2 = 0; q2 < s; ++q2) {
      double E2[4][4];
      for (int i = 0; i < 4; ++i)
        for (int j = 0; j < 4; ++j) {
          double acc = 0.0;
          for (int m = 0; m < 4; ++m) acc += E[i][m] * E[m][j];
          E2[i][j] = acc;
        }
      for (int i = 0; i < 4; ++i) for (int j = 0; j < 4; ++j) E[i][j] = E2[i][j];
    }
    for (int i = 0; i < 4; ++i)
      for (int j = 0; j < 4; ++j) Psh[i * 4 + j] = (float)E[i][j];
  } else if (tid == 64 || tid == 65) {
    // Apow table only (ALp dead — carry scan handled by k2)
    const int p = h * 2 + (tid - 64);
    double th = exp((double)thetas_log[p]);
    double g = exp(-exp((double)gamma_log[h]));
    double ar = g * cos(th), ai = g * sin(th);
    float2* Apw = (float2*)(ws + AP_OFF);
    double xr = 1.0, xi = 0.0;
    Apw[p] = make_float2(1.f, 0.f);
    for (int j = 1; j <= LCH; ++j) {
      double nr = xr * ar - xi * ai, ni = xr * ai + xi * ar;
      xr = nr; xi = ni;
      Apw[j * 128 + p] = make_float2((float)xr, (float)xi);
    }
  } else if (tid == 128) {
    double g = exp(-exp((double)gamma_log[h]));
    double tr = (double)red[0] + red[1] + red[2] + red[3];
    nrmsh = (float)sqrt((1.0 - g * g) / tr);
  }
  __syncthreads();

  unsigned short* Mbf = (unsigned short*)(ws + MB_OFF);
  unsigned int*   Cbd = (unsigned int*)(ws + CB_OFF);
  {
    float b0 = B_param[(h * 4 + 0) * 256 + tid];
    float b1 = B_param[(h * 4 + 1) * 256 + tid];
    float b2 = B_param[(h * 4 + 2) * 256 + tid];
    float b3 = B_param[(h * 4 + 3) * 256 + tid];
    float nrm = nrmsh;
#pragma unroll
    for (int N = 0; N < 4; ++N) {
      float acc = Psh[N * 4 + 0] * b0 + Psh[N * 4 + 1] * b1 +
                  Psh[N * 4 + 2] * b2 + Psh[N * 4 + 3] * b3;
      Mbf[(h * 4 + N) * 256 + tid] = (unsigned short)f2bfbits(nrm * acc);
    }
  }
  {
    float4 cv = *(const float4*)(C + (size_t)tid * 256 + h * 4);
    float o[4];
#pragma unroll
    for (int N = 0; N < 4; ++N)
      o[N] = cv.x * Psh[N * 4 + 0] + cv.y * Psh[N * 4 + 1] +
             cv.z * Psh[N * 4 + 2] + cv.w * Psh[N * 4 + 3];
    Cbd[(tid * 256 + h * 4) >> 1]       = pack2(o[0], o[1]);
    Cbd[((tid * 256 + h * 4) >> 1) + 1] = pack2(o[2], o[3]);
  }
}

// ---------------------------------------------------------------------------
// K1: stage u (dword-pair) -> GEMM1 -> scan -> Zst (coalesced) + totals.
// (unchanged from round 5, verified)
// ---------------------------------------------------------------------------
__global__ __launch_bounds__(256, 4) void k1_mfma(
    const float* __restrict__ u, float* __restrict__ ws) {
  __shared__ __align__(16) unsigned char smem[LCH * LDK * 2];   // 16896 B
  unsigned short* us = (unsigned short*)smem;   // u tile [t][LDK] shorts
  unsigned int*   wd = (unsigned int*)smem;     // same, as [t][LDW] dwords

  const int c = blockIdx.x, b = blockIdx.y;
  const int t0 = c * LCH;
  const int tid = threadIdx.x;
  const int L = tid & 63;
  const int w = __builtin_amdgcn_readfirstlane(tid >> 6);
  const int qh = L >> 4, l15 = L & 15;

  // ---- stage u[d][t0+t] -> wd[t][j] (j = d/2, pair-packed) ----
  {
    const int dp = tid >> 3;                // 0..31
    const int t4 = (tid & 7) * 4;           // 0..28
#pragma unroll
    for (int i = 0; i < 4; ++i) {
      int j = dp + 32 * i;                  // pair index 0..127
      float4 va = *(const float4*)(u + (size_t)(b * 256 + 2 * j) * TLEN + t0 + t4);
      float4 vb = *(const float4*)(u + (size_t)(b * 256 + 2 * j + 1) * TLEN + t0 + t4);
      float av[4] = {va.x, va.y, va.z, va.w};
      float bv[4] = {vb.x, vb.y, vb.z, vb.w};
#pragma unroll
      for (int dt = 0; dt < 4; ++dt)
        wd[(t4 + dt) * LDW + j] = pack2(av[dt], bv[dt]);
    }
  }
  __syncthreads();

  // ---- GEMM1: W[256][32] = M @ u_tile ----
  f32x4 acc[4][2];
#pragma unroll
  for (int rt = 0; rt < 4; ++rt)
#pragma unroll
    for (int tt = 0; tt < 2; ++tt) acc[rt][tt] = (f32x4){0.f, 0.f, 0.f, 0.f};
  {
    const unsigned short* Mbf = (const unsigned short*)(ws + MB_OFF);
#pragma unroll
    for (int ks = 0; ks < 8; ++ks) {
      short8 af[4], bf[2];
#pragma unroll
      for (int rt = 0; rt < 4; ++rt)
        af[rt] = *(const short8*)(Mbf + (size_t)(w * 64 + rt * 16 + l15) * 256 + ks * 32 + qh * 8);
#pragma unroll
      for (int tt = 0; tt < 2; ++tt)
        bf[tt] = *(const short8*)(us + (tt * 16 + l15) * LDK + ks * 32 + qh * 8);
#pragma unroll
      for (int rt = 0; rt < 4; ++rt)
#pragma unroll
        for (int tt = 0; tt < 2; ++tt)
          acc[rt][tt] = __builtin_amdgcn_mfma_f32_16x16x32_bf16(af[rt], bf[tt], acc[rt][tt], 0, 0, 0);
    }
  }
  __syncthreads();   // all us reads done before overwrite (alias)

  // ---- W -> wd[t][p] pair-packed bf16 (D: row=qh*4+q, col=l15) ----
#pragma unroll
  for (int rt = 0; rt < 4; ++rt) {
    int pbase = w * 32 + rt * 8 + qh * 2;   // dword index = state-row/2
#pragma unroll
    for (int tt = 0; tt < 2; ++tt) {
      int t = tt * 16 + l15;
      f32x4 a4 = acc[rt][tt];
      wd[t * LDW + pbase]     = pack2(a4[0], a4[1]);
      wd[t * LDW + pbase + 1] = pack2(a4[2], a4[3]);
    }
  }
  __syncthreads();

  // ---- local scan (fp32 state, bf16 storage), totals ----
  if (tid < 128) {
    const int p = tid;
    const float2* Apw = (const float2*)(ws + AP_OFF);
    float2 a = Apw[128 + p];       // a^1
    float zr = 0.f, zi = 0.f;
#pragma unroll
    for (int t = 0; t < LCH; ++t) {
      unsigned int wv = wd[t * LDW + p];
      float wr = bfbits2f(wv & 0xffffu), wi = bfbits2f(wv >> 16);
      float nr = fmaf(a.x, zr, fmaf(-a.y, zi, wr));
      float ni = fmaf(a.x, zi, fmaf(a.y, zr, wi));
      zr = nr; zi = ni;
      wd[t * LDW + p] = pack2(zr, zi);
    }
    ((float2*)(ws + TOT_OFF))[(c * BSZ + b) * 128 + p] = make_float2(zr, zi);
  }
  __syncthreads();

  // ---- local-z states -> Zst (per-block contiguous, coalesced) ----
  unsigned int* Zg = (unsigned int*)(ws + ZST_OFF) + (size_t)(c * BSZ + b) * 4096;
#pragma unroll
  for (int jj = 0; jj < 16; ++jj) {
    int idx = tid + 256 * jj;
    Zg[idx] = wd[(idx >> 7) * LDW + (idx & 127)];
  }
}

// ---------------------------------------------------------------------------
// K2: in-place exclusive scan of Tot over chunks: Tot[c] := Z_{c-1}.
//     Z_c = Tot_c + a^LCH * Z_{c-1}.  8 blocks (one per b) x 128 threads (p).
// ---------------------------------------------------------------------------
__global__ __launch_bounds__(128) void k2_carry(float* __restrict__ ws) {
  const int b = blockIdx.x;
  const int p = threadIdx.x;
  const float2* Apw = (const float2*)(ws + AP_OFF);
  float2* Tot = (float2*)(ws + TOT_OFF);
  const float2 aL = Apw[LCH * 128 + p];     // a^LCH
  float cr = 0.f, ci = 0.f;
#pragma unroll 4
  for (int c = 0; c < NCH; ++c) {
    float2* slot = Tot + (size_t)(c * BSZ + b) * 128 + p;
    float2 tv = *slot;
    *slot = make_float2(cr, ci);            // exclusive: carry entering chunk c
    float nr = fmaf(aL.x, cr, fmaf(-aL.y, ci, tv.x));
    float ni = fmaf(aL.x, ci, fmaf(aL.y, cr, tv.y));
    cr = nr; ci = ni;
  }
}

// ---------------------------------------------------------------------------
// K3: carry = one float2 load; fused reload+correct -> LDS z tile ->
//     MFMA GEMM2 -> out + D⊙u.
// ---------------------------------------------------------------------------
__global__ __launch_bounds__(256, 4) void k3_mfma(
    const float* __restrict__ u, const float* __restrict__ Dv,
    const float* __restrict__ ws, float* __restrict__ out) {
  __shared__ __align__(16) unsigned char smem[LCH * LDK * 2];
  unsigned int* wd = (unsigned int*)smem;       // z tile [t][LDW] dwords

  const int c = blockIdx.x, b = blockIdx.y;
  const int t0 = c * LCH;
  const int tid = threadIdx.x;
  const int L = tid & 63;
  const int w = __builtin_amdgcn_readfirstlane(tid >> 6);
  const int qh = L >> 4, l15 = L & 15;

  // ---- fused reload + carry-correct (p constant per thread) ----
  {
    const int p = tid & 127;
    const float2 cv = ((const float2*)(ws + TOT_OFF))[(size_t)(c * BSZ + b) * 128 + p];
    const float2* Apw = (const float2*)(ws + AP_OFF);
    const unsigned int* Zg = (const unsigned int*)(ws + ZST_OFF) + (size_t)(c * BSZ + b) * 4096;
#pragma unroll
    for (int jj = 0; jj < 16; ++jj) {
      int idx = tid + 256 * jj;
      int t = idx >> 7;
      unsigned int wv = Zg[idx];
      float2 ap = Apw[(t + 1) * 128 + p];
      float sr = fmaf(ap.x, cv.x, fmaf(-ap.y, cv.y, bfbits2f(wv & 0xffffu)));
      float si = fmaf(ap.x, cv.y, fmaf(ap.y, cv.x, bfbits2f(wv >> 16)));
      wd[t * LDW + p] = pack2(sr, si);
    }
  }
  __syncthreads();

  // ---- GEMM2: out_tile = C2 @ Z ----
  f32x4 acc[4][2];
#pragma unroll
  for (int rt = 0; rt < 4; ++rt)
#pragma unroll
    for (int tt = 0; tt < 2; ++tt) acc[rt][tt] = (f32x4){0.f, 0.f, 0.f, 0.f};
  {
    const unsigned short* Cbf = (const unsigned short*)(ws + CB_OFF);
    const unsigned short* zs  = (const unsigned short*)smem;
#pragma unroll
    for (int ks = 0; ks < 8; ++ks) {
      short8 af[4], bf[2];
#pragma unroll
      for (int rt = 0; rt < 4; ++rt)
        af[rt] = *(const short8*)(Cbf + (size_t)(w * 64 + rt * 16 + l15) * 256 + ks * 32 + qh * 8);
#pragma unroll
      for (int tt = 0; tt < 2; ++tt)
        bf[tt] = *(const short8*)(zs + (tt * 16 + l15) * LDK + ks * 32 + qh * 8);
#pragma unroll
      for (int rt = 0; rt < 4; ++rt)
#pragma unroll
        for (int tt = 0; tt < 2; ++tt)
          acc[rt][tt] = __builtin_amdgcn_mfma_f32_16x16x32_bf16(af[rt], bf[tt], acc[rt][tt], 0, 0, 0);
    }
  }

  // ---- epilogue: out = acc + D ⊙ u ----
  float dv[4][4];
#pragma unroll
  for (int rt = 0; rt < 4; ++rt)
#pragma unroll
    for (int q = 0; q < 4; ++q) dv[rt][q] = Dv[w * 64 + rt * 16 + qh * 4 + q];
#pragma unroll
  for (int rt = 0; rt < 4; ++rt) {
    int Dbase = w * 64 + rt * 16 + qh * 4;
#pragma unroll
    for (int tt = 0; tt < 2; ++tt) {
      int t = tt * 16 + l15;
      f32x4 a4 = acc[rt][tt];
      size_t obase = (size_t)(b * 256 + Dbase) * TLEN + t0 + t;
#pragma unroll
      for (int q = 0; q < 4; ++q)
        out[obase + (size_t)q * TLEN] = a4[q] + dv[rt][q] * u[obase + (size_t)q * TLEN];
    }
  }
}

extern "C" void kernel_launch(void* const* d_in, const int* in_sizes, int n_in,
                              void* d_out, int out_size, void* d_ws, size_t ws_size,
                              hipStream_t stream) {
  const float* u          = (const float*)d_in[0];
  const float* thetas_log = (const float*)d_in[1];
  const float* P_param    = (const float*)d_in[2];
  const float* B_param    = (const float*)d_in[3];
  const float* C          = (const float*)d_in[4];
  const float* Dvec       = (const float*)d_in[5];
  const float* gamma_log  = (const float*)d_in[6];
  float* out = (float*)d_out;
  float* ws  = (float*)d_ws;

  hipLaunchKernelGGL(k0_setup, dim3(64), dim3(256), 0, stream,
                     thetas_log, P_param, B_param, C, gamma_log, ws);
  hipLaunchKernelGGL(k1_mfma, dim3(NCH, BSZ), dim3(256), 0, stream, u, ws);
  hipLaunchKernelGGL(k2_carry, dim3(BSZ), dim3(128), 0, stream, ws);
  hipLaunchKernelGGL(k3_mfma, dim3(NCH, BSZ), dim3(256), 0, stream, u, Dvec, ws, out);
}

// Round 8
// 157.365 us; speedup vs baseline: 1.2495x; 1.0963x over previous
//
#include <hip/hip_runtime.h>
#include <math.h>

// ---------------------------------------------------------------------------
// RotSSM: out[b,Do,t] = C2 @ scan(M @ u)[.,b,t] + D ⊙ u[b,.,t]
//   k0 (64 blocks): trace/expm/norm/Apow table + M, C2.  (verified)
//   k1 (128x8 blocks, LCH=32): stage u -> MFMA GEMM1 -> local scan, scan
//      stores z DIRECTLY to Zst (coalesced 128x4B per t) + chunk totals.
//      (removes LDS round-trip + 1 barrier vs round 7)
//   k2 (8 blocks x 128 thr): exclusive scan of Tot over chunks, CHUNKED
//      PREFETCH: 16 batched loads -> 16 FMA+store. Amortizes load latency
//      16x vs round-7's aliased serial loop.
//   k3 (128x8 blocks): carry = one float2 load; fused reload+correct ->
//      LDS z tile -> MFMA GEMM2 -> out + D⊙u.  (verified)
//   Workspace layout identical to round-5/7 proven footprint (~18.3 MB).
// ---------------------------------------------------------------------------

typedef __attribute__((ext_vector_type(8))) short short8;   // 8 bf16 (4 VGPRs)
typedef __attribute__((ext_vector_type(4))) float f32x4;

#define TLEN 4096
#define LCH 32            // chunk length (t per block)
#define NCH 128           // number of chunks
#define BSZ 8
#define LDW 132           // dwords per [t] row (128 + 4 pad)
#define LDK 264           // shorts per [t] row (= LDW*2)

// workspace float offsets (identical to round 5/7)
constexpr int MB_OFF   = 0;                               // M bf16 [256][256]
constexpr int CB_OFF   = 32768;                           // C2 bf16 [256][256]
constexpr int AP_OFF   = 65536;                           // Apow  [LCH+1][128] float2
constexpr int ALP_OFF  = AP_OFF + (LCH + 1) * 256;        // (unused, kept for layout)
constexpr int TOT_OFF  = ALP_OFF + (NCH + 1) * 256;       // Tot/Carry [NCH][8][128] float2
constexpr int ZST_OFF  = TOT_OFF + NCH * BSZ * 256;       // Zst [NCH*8][4096] dwords

__device__ __forceinline__ float bfbits2f(unsigned int bits16) {
  union { unsigned int u; float f; } v; v.u = bits16 << 16; return v.f;
}
__device__ __forceinline__ unsigned int f2bfbits(float f) {
  union { float f; unsigned int u; } v; v.f = f;
  return (v.u + 0x7fffu + ((v.u >> 16) & 1u)) >> 16;   // RNE, finite inputs
}
__device__ __forceinline__ unsigned int pack2(float x, float y) {
  return f2bfbits(x) | (f2bfbits(y) << 16);
}

// ---------------------------------------------------------------------------
// K0: one block per head. trace -> {expm | Apow table | norm, separate waves}
//     -> M rows 4h..4h+3 and C2 cols 4h..4h+3.
// ---------------------------------------------------------------------------
__global__ __launch_bounds__(256) void k0_setup(
    const float* __restrict__ thetas_log, const float* __restrict__ P_param,
    const float* __restrict__ B_param, const float* __restrict__ C,
    const float* __restrict__ gamma_log, float* __restrict__ ws) {
  const int h = blockIdx.x;
  const int tid = threadIdx.x;
  __shared__ float red[4];
  __shared__ float Psh[16];
  __shared__ float nrmsh;

  {
    float4 v = *(const float4*)(B_param + (size_t)h * 1024 + tid * 4);
    float s = v.x * v.x + v.y * v.y + v.z * v.z + v.w * v.w;
#pragma unroll
    for (int off = 32; off > 0; off >>= 1) s += __shfl_down(s, off);
    if ((tid & 63) == 0) red[tid >> 6] = s;
  }
  __syncthreads();

  if (tid == 0) {
    double A[4][4], E[4][4], Tm[4][4];
    for (int i = 0; i < 4; ++i)
      for (int j = 0; j < 4; ++j)
        A[i][j] = (double)P_param[h * 16 + i * 4 + j] - (double)P_param[h * 16 + j * 4 + i];
    double fro = 0.0;
    for (int i = 0; i < 4; ++i) for (int j = 0; j < 4; ++j) fro += A[i][j] * A[i][j];
    fro = sqrt(fro);
    int s = 0;
    while (fro > 0.25 && s < 30) { fro *= 0.5; ++s; }
    double scl = 1.0;
    for (int q2 = 0; q2 < s; ++q2) scl *= 0.5;
    for (int i = 0; i < 4; ++i) for (int j = 0; j < 4; ++j) A[i][j] *= scl;
    for (int i = 0; i < 4; ++i)
      for (int j = 0; j < 4; ++j) { E[i][j] = (i == j) ? 1.0 : 0.0; Tm[i][j] = E[i][j]; }
    for (int k = 1; k <= 16; ++k) {
      double Tn[4][4];
      for (int i = 0; i < 4; ++i)
        for (int j = 0; j < 4; ++j) {
          double acc = 0.0;
          for (int m = 0; m < 4; ++m) acc += Tm[i][m] * A[m][j];
          Tn[i][j] = acc / (double)k;
        }
      for (int i = 0; i < 4; ++i)
        for (int j = 0; j < 4; ++j) { Tm[i][j] = Tn[i][j]; E[i][j] += Tn[i][j]; }
    }
    for (int q2 = 0; q2 < s; ++q2) {
      double E2[4][4];
      for (int i = 0; i < 4; ++i)
        for (int j = 0; j < 4; ++j) {
          double acc = 0.0;
          for (int m = 0; m < 4; ++m) acc += E[i][m] * E[m][j];
          E2[i][j] = acc;
        }
      for (int i = 0; i < 4; ++i) for (int j = 0; j < 4; ++j) E[i][j] = E2[i][j];
    }
    for (int i = 0; i < 4; ++i)
      for (int j = 0; j < 4; ++j) Psh[i * 4 + j] = (float)E[i][j];
  } else if (tid == 64 || tid == 65) {
    const int p = h * 2 + (tid - 64);
    double th = exp((double)thetas_log[p]);
    double g = exp(-exp((double)gamma_log[h]));
    double ar = g * cos(th), ai = g * sin(th);
    float2* Apw = (float2*)(ws + AP_OFF);
    double xr = 1.0, xi = 0.0;
    Apw[p] = make_float2(1.f, 0.f);
    for (int j = 1; j <= LCH; ++j) {
      double nr = xr * ar - xi * ai, ni = xr * ai + xi * ar;
      xr = nr; xi = ni;
      Apw[j * 128 + p] = make_float2((float)xr, (float)xi);
    }
  } else if (tid == 128) {
    double g = exp(-exp((double)gamma_log[h]));
    double tr = (double)red[0] + red[1] + red[2] + red[3];
    nrmsh = (float)sqrt((1.0 - g * g) / tr);
  }
  __syncthreads();

  unsigned short* Mbf = (unsigned short*)(ws + MB_OFF);
  unsigned int*   Cbd = (unsigned int*)(ws + CB_OFF);
  {
    float b0 = B_param[(h * 4 + 0) * 256 + tid];
    float b1 = B_param[(h * 4 + 1) * 256 + tid];
    float b2 = B_param[(h * 4 + 2) * 256 + tid];
    float b3 = B_param[(h * 4 + 3) * 256 + tid];
    float nrm = nrmsh;
#pragma unroll
    for (int N = 0; N < 4; ++N) {
      float acc = Psh[N * 4 + 0] * b0 + Psh[N * 4 + 1] * b1 +
                  Psh[N * 4 + 2] * b2 + Psh[N * 4 + 3] * b3;
      Mbf[(h * 4 + N) * 256 + tid] = (unsigned short)f2bfbits(nrm * acc);
    }
  }
  {
    float4 cv = *(const float4*)(C + (size_t)tid * 256 + h * 4);
    float o[4];
#pragma unroll
    for (int N = 0; N < 4; ++N)
      o[N] = cv.x * Psh[N * 4 + 0] + cv.y * Psh[N * 4 + 1] +
             cv.z * Psh[N * 4 + 2] + cv.w * Psh[N * 4 + 3];
    Cbd[(tid * 256 + h * 4) >> 1]       = pack2(o[0], o[1]);
    Cbd[((tid * 256 + h * 4) >> 1) + 1] = pack2(o[2], o[3]);
  }
}

// ---------------------------------------------------------------------------
// K1: stage u (dword-pair) -> GEMM1 -> scan with DIRECT global z-store.
//     3 barriers (was 4), no LDS z round-trip.
// ---------------------------------------------------------------------------
__global__ __launch_bounds__(256, 4) void k1_mfma(
    const float* __restrict__ u, float* __restrict__ ws) {
  __shared__ __align__(16) unsigned char smem[LCH * LDK * 2];   // 16896 B
  unsigned short* us = (unsigned short*)smem;   // u tile [t][LDK] shorts
  unsigned int*   wd = (unsigned int*)smem;     // same, as [t][LDW] dwords

  const int c = blockIdx.x, b = blockIdx.y;
  const int t0 = c * LCH;
  const int tid = threadIdx.x;
  const int L = tid & 63;
  const int w = __builtin_amdgcn_readfirstlane(tid >> 6);
  const int qh = L >> 4, l15 = L & 15;

  // ---- stage u[d][t0+t] -> wd[t][j] (j = d/2, pair-packed) ----
  {
    const int dp = tid >> 3;                // 0..31
    const int t4 = (tid & 7) * 4;           // 0..28
#pragma unroll
    for (int i = 0; i < 4; ++i) {
      int j = dp + 32 * i;                  // pair index 0..127
      float4 va = *(const float4*)(u + (size_t)(b * 256 + 2 * j) * TLEN + t0 + t4);
      float4 vb = *(const float4*)(u + (size_t)(b * 256 + 2 * j + 1) * TLEN + t0 + t4);
      float av[4] = {va.x, va.y, va.z, va.w};
      float bv[4] = {vb.x, vb.y, vb.z, vb.w};
#pragma unroll
      for (int dt = 0; dt < 4; ++dt)
        wd[(t4 + dt) * LDW + j] = pack2(av[dt], bv[dt]);
    }
  }
  __syncthreads();

  // ---- GEMM1: W[256][32] = M @ u_tile ----
  f32x4 acc[4][2];
#pragma unroll
  for (int rt = 0; rt < 4; ++rt)
#pragma unroll
    for (int tt = 0; tt < 2; ++tt) acc[rt][tt] = (f32x4){0.f, 0.f, 0.f, 0.f};
  {
    const unsigned short* Mbf = (const unsigned short*)(ws + MB_OFF);
#pragma unroll
    for (int ks = 0; ks < 8; ++ks) {
      short8 af[4], bf[2];
#pragma unroll
      for (int rt = 0; rt < 4; ++rt)
        af[rt] = *(const short8*)(Mbf + (size_t)(w * 64 + rt * 16 + l15) * 256 + ks * 32 + qh * 8);
#pragma unroll
      for (int tt = 0; tt < 2; ++tt)
        bf[tt] = *(const short8*)(us + (tt * 16 + l15) * LDK + ks * 32 + qh * 8);
#pragma unroll
      for (int rt = 0; rt < 4; ++rt)
#pragma unroll
        for (int tt = 0; tt < 2; ++tt)
          acc[rt][tt] = __builtin_amdgcn_mfma_f32_16x16x32_bf16(af[rt], bf[tt], acc[rt][tt], 0, 0, 0);
    }
  }
  __syncthreads();   // all us reads done before overwrite (alias)

  // ---- W -> wd[t][p] pair-packed bf16 (D: row=qh*4+q, col=l15) ----
#pragma unroll
  for (int rt = 0; rt < 4; ++rt) {
    int pbase = w * 32 + rt * 8 + qh * 2;   // dword index = state-row/2
#pragma unroll
    for (int tt = 0; tt < 2; ++tt) {
      int t = tt * 16 + l15;
      f32x4 a4 = acc[rt][tt];
      wd[t * LDW + pbase]     = pack2(a4[0], a4[1]);
      wd[t * LDW + pbase + 1] = pack2(a4[2], a4[3]);
    }
  }
  __syncthreads();

  // ---- local scan (fp32 state), z -> Zst DIRECT (coalesced), totals ----
  if (tid < 128) {
    const int p = tid;
    const float2* Apw = (const float2*)(ws + AP_OFF);
    unsigned int* Zg = (unsigned int*)(ws + ZST_OFF) + (size_t)(c * BSZ + b) * 4096;
    float2 a = Apw[128 + p];       // a^1
    float zr = 0.f, zi = 0.f;
#pragma unroll
    for (int t = 0; t < LCH; ++t) {
      unsigned int wv = wd[t * LDW + p];
      float wr = bfbits2f(wv & 0xffffu), wi = bfbits2f(wv >> 16);
      float nr = fmaf(a.x, zr, fmaf(-a.y, zi, wr));
      float ni = fmaf(a.x, zi, fmaf(a.y, zr, wi));
      zr = nr; zi = ni;
      Zg[t * 128 + p] = pack2(zr, zi);     // 128 thr x 4B = 512B coalesced
    }
    ((float2*)(ws + TOT_OFF))[(c * BSZ + b) * 128 + p] = make_float2(zr, zi);
  }
}

// ---------------------------------------------------------------------------
// K2: exclusive scan of Tot over chunks, chunked prefetch (16-deep).
//     Tot[c] := Z_{c-1};  Z_c = Tot_c + a^LCH * Z_{c-1}.
// ---------------------------------------------------------------------------
__global__ __launch_bounds__(128) void k2_carry(float* __restrict__ ws) {
  const int b = blockIdx.x;
  const int p = threadIdx.x;
  const float2* Apw = (const float2*)(ws + AP_OFF);
  float2* Tot = (float2*)(ws + TOT_OFF);
  const float2 aL = Apw[LCH * 128 + p];     // a^LCH
  float cr = 0.f, ci = 0.f;
  for (int c0 = 0; c0 < NCH; c0 += 16) {
    float2 tv[16];
#pragma unroll
    for (int k = 0; k < 16; ++k)
      tv[k] = Tot[(size_t)((c0 + k) * BSZ + b) * 128 + p];   // 16 loads in flight
#pragma unroll
    for (int k = 0; k < 16; ++k) {
      Tot[(size_t)((c0 + k) * BSZ + b) * 128 + p] = make_float2(cr, ci);
      float nr = fmaf(aL.x, cr, fmaf(-aL.y, ci, tv[k].x));
      float ni = fmaf(aL.x, ci, fmaf(aL.y, cr, tv[k].y));
      cr = nr; ci = ni;
    }
  }
}

// ---------------------------------------------------------------------------
// K3: carry = one float2 load; fused reload+correct -> LDS z tile ->
//     MFMA GEMM2 -> out + D⊙u.  (verified round 7)
// ---------------------------------------------------------------------------
__global__ __launch_bounds__(256, 4) void k3_mfma(
    const float* __restrict__ u, const float* __restrict__ Dv,
    const float* __restrict__ ws, float* __restrict__ out) {
  __shared__ __align__(16) unsigned char smem[LCH * LDK * 2];
  unsigned int* wd = (unsigned int*)smem;       // z tile [t][LDW] dwords

  const int c = blockIdx.x, b = blockIdx.y;
  const int t0 = c * LCH;
  const int tid = threadIdx.x;
  const int L = tid & 63;
  const int w = __builtin_amdgcn_readfirstlane(tid >> 6);
  const int qh = L >> 4, l15 = L & 15;

  // ---- fused reload + carry-correct (p constant per thread) ----
  {
    const int p = tid & 127;
    const float2 cv = ((const float2*)(ws + TOT_OFF))[(size_t)(c * BSZ + b) * 128 + p];
    const float2* Apw = (const float2*)(ws + AP_OFF);
    const unsigned int* Zg = (const unsigned int*)(ws + ZST_OFF) + (size_t)(c * BSZ + b) * 4096;
#pragma unroll
    for (int jj = 0; jj < 16; ++jj) {
      int idx = tid + 256 * jj;
      int t = idx >> 7;
      unsigned int wv = Zg[idx];
      float2 ap = Apw[(t + 1) * 128 + p];
      float sr = fmaf(ap.x, cv.x, fmaf(-ap.y, cv.y, bfbits2f(wv & 0xffffu)));
      float si = fmaf(ap.x, cv.y, fmaf(ap.y, cv.x, bfbits2f(wv >> 16)));
      wd[t * LDW + p] = pack2(sr, si);
    }
  }
  __syncthreads();

  // ---- GEMM2: out_tile = C2 @ Z ----
  f32x4 acc[4][2];
#pragma unroll
  for (int rt = 0; rt < 4; ++rt)
#pragma unroll
    for (int tt = 0; tt < 2; ++tt) acc[rt][tt] = (f32x4){0.f, 0.f, 0.f, 0.f};
  {
    const unsigned short* Cbf = (const unsigned short*)(ws + CB_OFF);
    const unsigned short* zs  = (const unsigned short*)smem;
#pragma unroll
    for (int ks = 0; ks < 8; ++ks) {
      short8 af[4], bf[2];
#pragma unroll
      for (int rt = 0; rt < 4; ++rt)
        af[rt] = *(const short8*)(Cbf + (size_t)(w * 64 + rt * 16 + l15) * 256 + ks * 32 + qh * 8);
#pragma unroll
      for (int tt = 0; tt < 2; ++tt)
        bf[tt] = *(const short8*)(zs + (tt * 16 + l15) * LDK + ks * 32 + qh * 8);
#pragma unroll
      for (int rt = 0; rt < 4; ++rt)
#pragma unroll
        for (int tt = 0; tt < 2; ++tt)
          acc[rt][tt] = __builtin_amdgcn_mfma_f32_16x16x32_bf16(af[rt], bf[tt], acc[rt][tt], 0, 0, 0);
    }
  }

  // ---- epilogue: out = acc + D ⊙ u ----
  float dv[4][4];
#pragma unroll
  for (int rt = 0; rt < 4; ++rt)
#pragma unroll
    for (int q = 0; q < 4; ++q) dv[rt][q] = Dv[w * 64 + rt * 16 + qh * 4 + q];
#pragma unroll
  for (int rt = 0; rt < 4; ++rt) {
    int Dbase = w * 64 + rt * 16 + qh * 4;
#pragma unroll
    for (int tt = 0; tt < 2; ++tt) {
      int t = tt * 16 + l15;
      f32x4 a4 = acc[rt][tt];
      size_t obase = (size_t)(b * 256 + Dbase) * TLEN + t0 + t;
#pragma unroll
      for (int q = 0; q < 4; ++q)
        out[obase + (size_t)q * TLEN] = a4[q] + dv[rt][q] * u[obase + (size_t)q * TLEN];
    }
  }
}

extern "C" void kernel_launch(void* const* d_in, const int* in_sizes, int n_in,
                              void* d_out, int out_size, void* d_ws, size_t ws_size,
                              hipStream_t stream) {
  const float* u          = (const float*)d_in[0];
  const float* thetas_log = (const float*)d_in[1];
  const float* P_param    = (const float*)d_in[2];
  const float* B_param    = (const float*)d_in[3];
  const float* C          = (const float*)d_in[4];
  const float* Dvec       = (const float*)d_in[5];
  const float* gamma_log  = (const float*)d_in[6];
  float* out = (float*)d_out;
  float* ws  = (float*)d_ws;

  hipLaunchKernelGGL(k0_setup, dim3(64), dim3(256), 0, stream,
                     thetas_log, P_param, B_param, C, gamma_log, ws);
  hipLaunchKernelGGL(k1_mfma, dim3(NCH, BSZ), dim3(256), 0, stream, u, ws);
  hipLaunchKernelGGL(k2_carry, dim3(BSZ), dim3(128), 0, stream, ws);
  hipLaunchKernelGGL(k3_mfma, dim3(NCH, BSZ), dim3(256), 0, stream, u, Dvec, ws, out);
}